// Round 1
// baseline (1500.340 us; speedup 1.0000x reference)
//
#include <hip/hip_runtime.h>
#include <stdint.h>

#define MIN_NORM 1e-15f
#define MAXN     0.996f            // (1 - 4e-3) / sqrt(c), c = 1
#define ART_CLIP (1.0f - 1e-7f)

typedef __attribute__((ext_vector_type(8)))  short bf16x8;
typedef __attribute__((ext_vector_type(16))) float f32x16;

__device__ __forceinline__ float wave_sum(float v) {
#pragma unroll
  for (int m = 1; m < 64; m <<= 1) v += __shfl_xor(v, m, 64);
  return v;
}

__device__ __forceinline__ uint32_t bf16rne(float f) {
  uint32_t u = __float_as_uint(f);
  return (u + 0x7FFFu + ((u >> 16) & 1u)) >> 16;
}

// pack two fp32 (even, odd) into one dword of bf16x2 via byte-perm (truncation)
__device__ __forceinline__ bf16x8 pack_a(float4 lo, float4 hi) {
  union { uint32_t u[4]; bf16x8 v; } r;
  r.u[0] = __builtin_amdgcn_perm(__float_as_uint(lo.y), __float_as_uint(lo.x), 0x07060302u);
  r.u[1] = __builtin_amdgcn_perm(__float_as_uint(lo.w), __float_as_uint(lo.z), 0x07060302u);
  r.u[2] = __builtin_amdgcn_perm(__float_as_uint(hi.y), __float_as_uint(hi.x), 0x07060302u);
  r.u[3] = __builtin_amdgcn_perm(__float_as_uint(hi.w), __float_as_uint(hi.z), 0x07060302u);
  return r.v;
}

// ------------------------------------------------------------------
// Kernel 1: HypLinear row pipeline  (mobius_matvec -> proj -> mobius_add
// with hyp_bias -> proj -> logmap0), writes xt as bf16 in the MFMA-B
// swizzled layout: flat = (k>>3)*1024 + n*8 + (k&7)   (k = row, n = col)
// Block: 256 thr = 4 waves; wave handles 8 consecutive rows; grid 512.
// ------------------------------------------------------------------
__global__ __launch_bounds__(256, 2) void k1_rowpipe(
    const float* __restrict__ x, const float* __restrict__ W,
    const float* __restrict__ bias, uint16_t* __restrict__ xt) {
  __shared__ float Wl[128 * 132];   // padded leading dim: bank-conflict-free
  __shared__ float hb[128];
  __shared__ float hby2;

  const int tid = threadIdx.x;
  for (int i = tid; i < 128 * 128; i += 256)
    Wl[(i >> 7) * 132 + (i & 127)] = W[i];

  if (tid < 64) {  // wave 0: hyp_bias = proj(expmap0(bias))
    float b0 = bias[tid], b1 = bias[tid + 64];
    float bn2 = wave_sum(b0 * b0 + b1 * b1);
    float bn = fmaxf(sqrtf(bn2), MIN_NORM);
    float t = tanhf(bn);
    float sc = t / bn;
    if (t > MAXN) sc = MAXN / bn;
    float h0 = b0 * sc, h1 = b1 * sc;
    float y2 = wave_sum(h0 * h0 + h1 * h1);
    hb[tid] = h0; hb[tid + 64] = h1;
    if (tid == 0) hby2 = y2;
  }
  __syncthreads();

  const int wid = tid >> 6, lane = tid & 63;
  const int row0 = blockIdx.x * 32 + wid * 8;   // multiple of 8
  const float hb0 = hb[lane], hb1 = hb[lane + 64];
  const float y2 = hby2;

  float o0[8], o1[8];
#pragma unroll
  for (int rr = 0; rr < 8; ++rr) {
    const float* xr = x + (size_t)(row0 + rr) * 128;
    float acc0 = 0.f, acc1 = 0.f, xn2 = 0.f;
#pragma unroll
    for (int k = 0; k < 128; k += 4) {
      float4 xv = *(const float4*)(xr + k);                 // broadcast (L1)
      float4 w0 = *(const float4*)(&Wl[lane * 132 + k]);
      float4 w1 = *(const float4*)(&Wl[(lane + 64) * 132 + k]);
      xn2 = fmaf(xv.x, xv.x, fmaf(xv.y, xv.y, fmaf(xv.z, xv.z, fmaf(xv.w, xv.w, xn2))));
      acc0 = fmaf(xv.x, w0.x, fmaf(xv.y, w0.y, fmaf(xv.z, w0.z, fmaf(xv.w, w0.w, acc0))));
      acc1 = fmaf(xv.x, w1.x, fmaf(xv.y, w1.y, fmaf(xv.z, w1.z, fmaf(xv.w, w1.w, acc1))));
    }
    // mobius_matvec epilogue
    float mxn2 = wave_sum(acc0 * acc0 + acc1 * acc1);
    float xn = fmaxf(sqrtf(xn2), MIN_NORM);
    float mxn = fmaxf(sqrtf(mxn2), MIN_NORM);
    float a = atanhf(fminf(xn, ART_CLIP));
    float t = tanhf(a * (mxn / xn));
    float rs = t / mxn;
    float r0v = acc0 * rs, r1v = acc1 * rs;
    if (t > MAXN) { float f = MAXN / t; r0v *= f; r1v *= f; }   // proj(mv): ||mv|| == t
    // mobius_add(res, hyp_bias)
    float x2 = wave_sum(r0v * r0v + r1v * r1v);
    float xy = wave_sum(r0v * hb0 + r1v * hb1);
    float cx = 1.f + 2.f * xy + y2;
    float cy = 1.f - x2;
    float den = fmaxf(1.f + 2.f * xy + x2 * y2, MIN_NORM);
    float h0v = (cx * r0v + cy * hb0) / den;
    float h1v = (cx * r1v + cy * hb1) / den;
    // proj(h) then logmap0
    float hn2 = wave_sum(h0v * h0v + h1v * h1v);
    float hn = fmaxf(sqrtf(hn2), MIN_NORM);
    if (hn > MAXN) { float f = MAXN / hn; h0v *= f; h1v *= f; hn = MAXN; }
    float la = atanhf(fminf(hn, ART_CLIP)) / hn;
    o0[rr] = h0v * la;
    o1[rr] = h1v * la;
  }

  // packed, coalesced store of 8 rows (j = k&7 contiguous per lane)
  const size_t base = (size_t)(row0 >> 3) * 1024;
  uint4 v;
  v.x = (bf16rne(o0[1]) << 16) | bf16rne(o0[0]);
  v.y = (bf16rne(o0[3]) << 16) | bf16rne(o0[2]);
  v.z = (bf16rne(o0[5]) << 16) | bf16rne(o0[4]);
  v.w = (bf16rne(o0[7]) << 16) | bf16rne(o0[6]);
  *(uint4*)(xt + base + (size_t)lane * 8) = v;
  v.x = (bf16rne(o1[1]) << 16) | bf16rne(o1[0]);
  v.y = (bf16rne(o1[3]) << 16) | bf16rne(o1[2]);
  v.z = (bf16rne(o1[5]) << 16) | bf16rne(o1[4]);
  v.w = (bf16rne(o1[7]) << 16) | bf16rne(o1[6]);
  *(uint4*)(xt + base + (size_t)(lane + 64) * 8) = v;
}

// ------------------------------------------------------------------
// Kernel 2: support = adj @ xt.  1 wave/block, 32 rows x 128 cols x 8192 K
// (split-K x2).  adj fp32 loaded directly in MFMA-A-fragment layout,
// converted to bf16 in registers; xt loaded as pre-swizzled B fragments.
// No LDS, no barriers: register double-buffer keeps the HBM stream deep.
// ------------------------------------------------------------------
__global__ __launch_bounds__(64) void k2_gemm(const float* __restrict__ adj,
                                              const uint16_t* __restrict__ xt,
                                              float* __restrict__ part) {
  const int lane  = threadIdx.x;
  const int mrow  = lane & 31;
  const int half8 = lane >> 5;
  const int r0    = (blockIdx.x >> 1) * 32;
  const int khalf = blockIdx.x & 1;
  const int kbase = khalf * 8192;

  const float*    aptr = adj + (size_t)(r0 + mrow) * 16384 + kbase + half8 * 8;
  const uint16_t* bptr = xt + ((size_t)(kbase >> 3) + half8) * 1024 + (size_t)mrow * 8;

  f32x16 acc[4];
#pragma unroll
  for (int c = 0; c < 4; ++c)
#pragma unroll
    for (int r = 0; r < 16; ++r) acc[c][r] = 0.0f;

  float4 Alo[2], Ahi[2];
  bf16x8 Bf[2][4];
#pragma unroll
  for (int s = 0; s < 2; ++s) {
    const float* ap = aptr + (size_t)s * 16;
    Alo[s] = *(const float4*)ap;
    Ahi[s] = *(const float4*)(ap + 4);
    const uint16_t* bp = bptr + (size_t)s * 2048;
    Bf[s][0] = *(const bf16x8*)(bp);
    Bf[s][1] = *(const bf16x8*)(bp + 256);
    Bf[s][2] = *(const bf16x8*)(bp + 512);
    Bf[s][3] = *(const bf16x8*)(bp + 768);
  }

#pragma unroll 2
  for (int it = 0; it < 512; ++it) {
    const int s = it & 1;
    bf16x8 af = pack_a(Alo[s], Ahi[s]);
    acc[0] = __builtin_amdgcn_mfma_f32_32x32x16_bf16(af, Bf[s][0], acc[0], 0, 0, 0);
    acc[1] = __builtin_amdgcn_mfma_f32_32x32x16_bf16(af, Bf[s][1], acc[1], 0, 0, 0);
    acc[2] = __builtin_amdgcn_mfma_f32_32x32x16_bf16(af, Bf[s][2], acc[2], 0, 0, 0);
    acc[3] = __builtin_amdgcn_mfma_f32_32x32x16_bf16(af, Bf[s][3], acc[3], 0, 0, 0);
    int itn = it + 2; if (itn > 511) itn = 511;      // tail: redundant reload
    const float* ap = aptr + (size_t)itn * 16;
    Alo[s] = *(const float4*)ap;
    Ahi[s] = *(const float4*)(ap + 4);
    const uint16_t* bp = bptr + (size_t)itn * 2048;
    Bf[s][0] = *(const bf16x8*)(bp);
    Bf[s][1] = *(const bf16x8*)(bp + 256);
    Bf[s][2] = *(const bf16x8*)(bp + 512);
    Bf[s][3] = *(const bf16x8*)(bp + 768);
  }

  // C/D layout (verified): col = lane&31, row = (r&3) + 8*(r>>2) + 4*(lane>>5)
  float* outp = part + (size_t)khalf * (16384 * 128);
#pragma unroll
  for (int c = 0; c < 4; ++c)
#pragma unroll
    for (int r = 0; r < 16; ++r) {
      int rowl = (r & 3) + 8 * (r >> 2) + 4 * half8;
      outp[(size_t)(r0 + rowl) * 128 + c * 32 + mrow] = acc[c][r];
    }
}

// ------------------------------------------------------------------
// Kernel 3: h = proj(expmap0(p0+p1)); xt = relu(logmap0(h));
//           out = proj(expmap0(xt)).   Wave per row.
// ------------------------------------------------------------------
__global__ __launch_bounds__(256) void k3_post(const float* __restrict__ part,
                                               float* __restrict__ outp) {
  const int tid = threadIdx.x, wid = tid >> 6, lane = tid & 63;
  const int row = blockIdx.x * 4 + wid;
  const float* p0 = part + (size_t)row * 128;
  const float* p1 = part + (size_t)(16384 * 128) + (size_t)row * 128;
  float s0 = p0[lane] + p1[lane];
  float s1 = p0[lane + 64] + p1[lane + 64];
  float sn2 = wave_sum(s0 * s0 + s1 * s1);
  float sn = fmaxf(sqrtf(sn2), MIN_NORM);
  float t = tanhf(sn);
  float es = t / sn;
  float h0 = s0 * es, h1 = s1 * es;
  float hn = t;                                   // ||h|| = tanh(sn)
  if (hn > MAXN) { float f = MAXN / hn; h0 *= f; h1 *= f; hn = MAXN; }
  float pn = fmaxf(hn, MIN_NORM);
  float la = atanhf(fminf(pn, ART_CLIP)) / pn;
  float u0 = fmaxf(h0 * la, 0.f), u1 = fmaxf(h1 * la, 0.f);   // relu in tangent
  float un2 = wave_sum(u0 * u0 + u1 * u1);
  float un = fmaxf(sqrtf(un2), MIN_NORM);
  float t2 = tanhf(un);
  float es2 = t2 / un;
  float o0 = u0 * es2, o1 = u1 * es2;
  if (t2 > MAXN) { float f = MAXN / t2; o0 *= f; o1 *= f; }
  outp[(size_t)row * 128 + lane] = o0;
  outp[(size_t)row * 128 + lane + 64] = o1;
}

extern "C" void kernel_launch(void* const* d_in, const int* in_sizes, int n_in,
                              void* d_out, int out_size, void* d_ws, size_t ws_size,
                              hipStream_t stream) {
  const float* x      = (const float*)d_in[0];
  const float* adj    = (const float*)d_in[1];
  const float* weight = (const float*)d_in[2];
  const float* bias   = (const float*)d_in[3];
  float* out = (float*)d_out;

  uint16_t* xt_sw = (uint16_t*)d_ws;                                  // 4 MB bf16
  float*    part  = (float*)((char*)d_ws + (size_t)4 * 1024 * 1024);  // 2 x 8 MB fp32

  hipLaunchKernelGGL(k1_rowpipe, dim3(512), dim3(256), 0, stream, x, weight, bias, xt_sw);
  hipLaunchKernelGGL(k2_gemm, dim3(1024), dim3(64), 0, stream, adj, xt_sw, part);
  hipLaunchKernelGGL(k3_post, dim3(4096), dim3(256), 0, stream, part, out);
}